// Round 16
// baseline (183.550 us; speedup 1.0000x reference)
//
#include <hip/hip_runtime.h>
#include <hip/hip_bf16.h>
#include <stdint.h>

#define NROWS 131072
#define BM 128
#define NK1 20
#define NK2 16
#define FSTR 1280
#define HSTR 1024

typedef __attribute__((ext_vector_type(8))) short bf16x8;
typedef __attribute__((ext_vector_type(4))) float f32x4;
typedef __attribute__((ext_vector_type(16))) float f32x16;
typedef __attribute__((ext_vector_type(4))) int i32x4;
typedef __attribute__((ext_vector_type(2))) unsigned int u32x2;

__device__ __forceinline__ unsigned f2bf(float x) {
    union { float f; unsigned u; } v; v.f = x;
    unsigned r = v.u + 0x7FFFu + ((v.u >> 16) & 1u);
    return r >> 16;
}

__device__ __forceinline__ unsigned pk2(float a, float b) {
    float2 t; t.x = a; t.y = b;
    __hip_bfloat162 h = __float22bfloat162_rn(t);
    union { __hip_bfloat162 h; unsigned u; } c; c.h = h;
    return c.u;
}

// LDS-only barrier: order LDS writes->reads without draining vmcnt.
__device__ __forceinline__ void lds_barrier() {
    asm volatile("s_waitcnt lgkmcnt(0)" ::: "memory");
    __builtin_amdgcn_sched_barrier(0);
    __builtin_amdgcn_s_barrier();
}

// ws layout:
// [0, 655360)            W1 bf16 PACKED [wv8][ks20][cn2][s2][lane64][8]  (32x32x16 A-frag order)
// [655360, 1179648)      W2 bf16 PACKED [wv8][ks16][cn2][s2][lane64][8]
// [1179648, +2560)       wf[640] f32 (trig rows pre-scaled by 1/2pi)
// [1182208, +2560)       bfv[640] f32 (cos folded to sin, pre-scaled)

__global__ void prep_kernel(
    const float* __restrict__ W1, const float* __restrict__ W2,
    const float* __restrict__ Wsx, const float* __restrict__ bsx,
    const float* __restrict__ Wcx, const float* __restrict__ bcx,
    const float* __restrict__ Wsy, const float* __restrict__ bsy,
    const float* __restrict__ Wcy, const float* __restrict__ bcy,
    const float* __restrict__ Wn, const float* __restrict__ bn,
    unsigned short* __restrict__ w1bp, unsigned short* __restrict__ w2bp,
    float* __restrict__ wf, float* __restrict__ bfv)
{
    int i = blockIdx.x * blockDim.x + threadIdx.x;
    const int n1 = 512 * 640;
    const int n2 = 512 * 512;
    if (i < n1) {
        // A-frag layout for v_mfma_f32_32x32x16_bf16: row=lane&31, k=(lane>>5)*8+e
        int e = i & 7, g = i >> 3;
        int lane = g & 63;
        int s  = (g >> 6) & 1;
        int cn = (g >> 7) & 1;
        int wk = g >> 8;                 // wv*20 + ks
        int ks = wk % 20, wv = wk / 20;
        int col = wv * 64 + cn * 32 + (lane & 31);
        int k   = ks * 32 + s * 16 + (lane >> 5) * 8 + e;
        w1bp[i] = (unsigned short)f2bf(W1[col * 640 + k]);
    } else if (i < n1 + n2) {
        int ii = i - n1;
        int e = ii & 7, g = ii >> 3;
        int lane = g & 63;
        int s  = (g >> 6) & 1;
        int cn = (g >> 7) & 1;
        int ks = (g >> 8) & 15, wv = g >> 12;
        int col = wv * 64 + cn * 32 + (lane & 31);
        int k   = ks * 32 + s * 16 + (lane >> 5) * 8 + e;
        w2bp[ii] = (unsigned short)f2bf(W2[col * 512 + k]);
    }
    if (i < 640) {
        const float HPI = 1.57079632679489662f;
        const float INV2PI = 0.15915494309189535f;
        float w, b;
        if (i < 512) {
            int j = i & 63, q = (i >> 6) & 3;
            if      (q == 0) { w = Wsx[j]; b = bsx[j]; }
            else if (q == 1) { w = Wcx[j]; b = bcx[j] + HPI; }
            else if (q == 2) { w = Wsy[j]; b = bsy[j]; }
            else             { w = Wcy[j]; b = bcy[j] + HPI; }
            w *= INV2PI; b *= INV2PI;    // revolutions for raw v_sin_f32
        } else { w = Wn[i - 512]; b = bn[i - 512]; }
        wf[i] = w; bfv[i] = b;
    }
}

// LDS: feats [128][640] bf16, stride 1280 B, swizzle ((row&15)<<4)^((row&16)<<2)
//      h     [128][512] bf16, stride 1024 B, same swizzle (aliased)

__global__ __launch_bounds__(512, 2) void mlp_kernel(
    const float* __restrict__ pf, const float* __restrict__ pt,
    const float* __restrict__ nm,
    const unsigned short* __restrict__ w1bp,
    const unsigned short* __restrict__ w2bp,
    const float* __restrict__ wf, const float* __restrict__ bfv,
    const float* __restrict__ b1, const float* __restrict__ b2,
    float* __restrict__ out)
{
    __shared__ __align__(16) unsigned char lds[163840];

    const int tid  = threadIdx.x;
    const int lane = tid & 63;
    const int wave = tid >> 6;          // 0..7, each owns 64 output cols
    const int l31  = lane & 31;
    const int l32  = lane >> 5;         // 0..1
    const int rowbase = blockIdx.x * BM;
    const int wcol = wave * 64;
    // af/h rows are rn*32 + l31 -> row&15 = lane&15, row&16 = lane&16
    const unsigned swz = (unsigned)(((lane & 15) << 4) ^ ((lane & 16) << 2));

    // v-input loads first (HBM latency overlaps W preload L2 latency)
    const int erow = tid >> 2;          // 0..127
    const int esub = tid & 3;
    const int grow = rowbase + erow;
    const float v0 = pf[grow * 2 + 0];
    const float v1 = pf[grow * 2 + 1];
    const float v2 = pt[grow * 2 + 0];
    const float v3 = pt[grow * 2 + 1];
    const float v4 = nm[grow];

    const unsigned short* w1p = w1bp + wave * (NK1 * 4 * 512) + lane * 8;
    const unsigned short* w2p = w2bp + wave * (NK2 * 4 * 512) + lane * 8;
#define W1FRAG(KS, CN, S) (*(const bf16x8*)(w1p + (((KS) * 4 + (CN) * 2 + (S)) * 512)))
#define W2FRAG(KS, CN, S) (*(const bf16x8*)(w2p + (((KS) * 4 + (CN) * 2 + (S)) * 512)))
// B-frag (activations): row = rn*32 + l31, k = ks*32 + s*16 + l32*8 (elements)
#define LDS_AF(KS, S, RN) (*(const bf16x8*)(lds + ((RN) * 32 + l31) * FSTR + \
                        (((unsigned)((KS) * 64 + (S) * 32 + l32 * 16)) ^ swz)))
#define LDS_HF(KS, S, RN) (*(const bf16x8*)(lds + ((RN) * 32 + l31) * HSTR + \
                        (((unsigned)((KS) * 64 + (S) * 32 + l32 * 16)) ^ swz)))

    // depth-2 rotating W-fragment buffers: [parity][cn][s]
    bf16x8 wb[2][2][2];
    #pragma unroll
    for (int p = 0; p < 2; ++p)
        #pragma unroll
        for (int cn = 0; cn < 2; ++cn)
            #pragma unroll
            for (int s = 0; s < 2; ++s)
                wb[p][cn][s] = W1FRAG(p, cn, s);

    // ---------------- encode: 4 threads/row, k = esub*8 + j*32 ----------------
    {
        const unsigned eswz = (unsigned)(((erow & 15) << 4) ^ ((erow & 16) << 2));
        #pragma unroll
        for (int j = 0; j < 20; ++j) {
            const int k = esub * 8 + j * 32;
            const float xv = (j < 4) ? v0 : (j < 8) ? v1 :
                             (j < 12) ? v2 : (j < 16) ? v3 : v4;
            const f32x4 w0 = *(const f32x4*)(wf + k);
            const f32x4 w1v = *(const f32x4*)(wf + k + 4);
            const f32x4 c0 = *(const f32x4*)(bfv + k);
            const f32x4 c1 = *(const f32x4*)(bfv + k + 4);
            float r[8];
            #pragma unroll
            for (int t = 0; t < 4; ++t) {
                float a0 = fmaf(xv, w0[t], c0[t]);
                float a1 = fmaf(xv, w1v[t], c1[t]);
                if (j < 16) {
                    asm("v_sin_f32 %0, %1" : "=v"(r[t])     : "v"(a0));
                    asm("v_sin_f32 %0, %1" : "=v"(r[t + 4]) : "v"(a1));
                } else { r[t] = a0; r[t + 4] = a1; }
            }
            i32x4 pk;
            pk.x = (int)pk2(r[0], r[1]);
            pk.y = (int)pk2(r[2], r[3]);
            pk.z = (int)pk2(r[4], r[5]);
            pk.w = (int)pk2(r[6], r[7]);
            *(i32x4*)(lds + erow * FSTR + (((unsigned)(k * 2)) ^ eswz)) = pk;
        }
    }

    f32x16 acc[4][2];
    #pragma unroll
    for (int a = 0; a < 4; ++a)
        #pragma unroll
        for (int b = 0; b < 2; ++b) acc[a][b] = (f32x16)(0.0f);

    lds_barrier();   // feats visible; W prefetches stay in flight

    // ---------------- layer 1: K=640, 32x32x16 MFMA, depth-2 W rotation --------
    #pragma unroll
    for (int ks = 0; ks < NK1; ++ks) {
        const int cur = ks & 1;
        __builtin_amdgcn_s_setprio(1);
        #pragma unroll
        for (int s = 0; s < 2; ++s) {
            #pragma unroll
            for (int rn = 0; rn < 4; ++rn) {
                bf16x8 af = LDS_AF(ks, s, rn);
                #pragma unroll
                for (int cn = 0; cn < 2; ++cn)
                    acc[rn][cn] = __builtin_amdgcn_mfma_f32_32x32x16_bf16(
                        wb[cur][cn][s], af, acc[rn][cn], 0, 0, 0);
            }
        }
        __builtin_amdgcn_s_setprio(0);
        if (ks + 2 < NK1) {
            #pragma unroll
            for (int cn = 0; cn < 2; ++cn)
                #pragma unroll
                for (int s = 0; s < 2; ++s)
                    wb[cur][cn][s] = W1FRAG(ks + 2, cn, s);
        } else {
            #pragma unroll
            for (int cn = 0; cn < 2; ++cn)
                #pragma unroll
                for (int s = 0; s < 2; ++s)
                    wb[cur][cn][s] = W2FRAG(ks + 2 - NK1, cn, s);
        }
    }

    lds_barrier();   // all feats reads done; h may alias feats

    // ---------------- bias + leaky -> h (bf16, 8B LDS writes) ----------------
    // C/D: out_row = rn*32 + (lane&31); out_col = cn*32 + (reg&3) + 8*(reg>>2) + 4*(lane>>5)
    #pragma unroll
    for (int rn = 0; rn < 4; ++rn) {
        const int row = rn * 32 + l31;
        #pragma unroll
        for (int cn = 0; cn < 2; ++cn) {
            #pragma unroll
            for (int rg = 0; rg < 4; ++rg) {
                const int colb = wcol + cn * 32 + rg * 8 + l32 * 4;
                const f32x4 bb = *(const f32x4*)(b1 + colb);
                float h0 = acc[rn][cn][rg * 4 + 0] + bb[0];
                float h1 = acc[rn][cn][rg * 4 + 1] + bb[1];
                float h2 = acc[rn][cn][rg * 4 + 2] + bb[2];
                float h3 = acc[rn][cn][rg * 4 + 3] + bb[3];
                h0 = (h0 >= 0.f) ? h0 : 0.01f * h0;
                h1 = (h1 >= 0.f) ? h1 : 0.01f * h1;
                h2 = (h2 >= 0.f) ? h2 : 0.01f * h2;
                h3 = (h3 >= 0.f) ? h3 : 0.01f * h3;
                u32x2 pk;
                pk.x = pk2(h0, h1);
                pk.y = pk2(h2, h3);
                *(u32x2*)(lds + row * HSTR + (((unsigned)(colb * 2)) ^ swz)) = pk;
            }
        }
    }

    #pragma unroll
    for (int a = 0; a < 4; ++a)
        #pragma unroll
        for (int b = 0; b < 2; ++b) acc[a][b] = (f32x16)(0.0f);

    lds_barrier();   // h visible

    // ---------------- layer 2: K=512 ----------------
    #pragma unroll
    for (int ks = 0; ks < NK2; ++ks) {
        const int cur = ks & 1;
        __builtin_amdgcn_s_setprio(1);
        #pragma unroll
        for (int s = 0; s < 2; ++s) {
            #pragma unroll
            for (int rn = 0; rn < 4; ++rn) {
                bf16x8 hf = LDS_HF(ks, s, rn);
                #pragma unroll
                for (int cn = 0; cn < 2; ++cn)
                    acc[rn][cn] = __builtin_amdgcn_mfma_f32_32x32x16_bf16(
                        wb[cur][cn][s], hf, acc[rn][cn], 0, 0, 0);
            }
        }
        __builtin_amdgcn_s_setprio(0);
        if (ks + 2 < NK2) {
            #pragma unroll
            for (int cn = 0; cn < 2; ++cn)
                #pragma unroll
                for (int s = 0; s < 2; ++s)
                    wb[cur][cn][s] = W2FRAG(ks + 2, cn, s);
        }
    }

    // ---------------- epilogue: bias + float4 stores ----------------
    #pragma unroll
    for (int rn = 0; rn < 4; ++rn) {
        const int row = rowbase + rn * 32 + l31;
        #pragma unroll
        for (int cn = 0; cn < 2; ++cn) {
            #pragma unroll
            for (int rg = 0; rg < 4; ++rg) {
                const int colb = wcol + cn * 32 + rg * 8 + l32 * 4;
                const f32x4 bb = *(const f32x4*)(b2 + colb);
                f32x4 o;
                o.x = acc[rn][cn][rg * 4 + 0] + bb[0];
                o.y = acc[rn][cn][rg * 4 + 1] + bb[1];
                o.z = acc[rn][cn][rg * 4 + 2] + bb[2];
                o.w = acc[rn][cn][rg * 4 + 3] + bb[3];
                *(f32x4*)(out + row * 512 + colb) = o;
            }
        }
    }
}

extern "C" void kernel_launch(void* const* d_in, const int* in_sizes, int n_in,
                              void* d_out, int out_size, void* d_ws, size_t ws_size,
                              hipStream_t stream)
{
    (void)in_sizes; (void)n_in; (void)out_size; (void)ws_size;
    const float* pf  = (const float*)d_in[0];
    const float* pt  = (const float*)d_in[1];
    const float* nm  = (const float*)d_in[2];
    const float* Wsx = (const float*)d_in[3];
    const float* bsx = (const float*)d_in[4];
    const float* Wcx = (const float*)d_in[5];
    const float* bcx = (const float*)d_in[6];
    const float* Wsy = (const float*)d_in[7];
    const float* bsy = (const float*)d_in[8];
    const float* Wcy = (const float*)d_in[9];
    const float* bcy = (const float*)d_in[10];
    const float* Wn  = (const float*)d_in[11];
    const float* bn  = (const float*)d_in[12];
    const float* W1  = (const float*)d_in[13];
    const float* b1  = (const float*)d_in[14];
    const float* W2  = (const float*)d_in[15];
    const float* b2  = (const float*)d_in[16];

    unsigned char* ws = (unsigned char*)d_ws;
    unsigned short* w1bp = (unsigned short*)(ws);
    unsigned short* w2bp = (unsigned short*)(ws + 512 * 640 * 2);
    float* wf  = (float*)(ws + 512 * 640 * 2 + 512 * 512 * 2);
    float* bfv = (float*)(ws + 512 * 640 * 2 + 512 * 512 * 2 + 640 * 4);

    const int prep_threads = 512 * 640 + 512 * 512;
    prep_kernel<<<(prep_threads + 255) / 256, 256, 0, stream>>>(
        W1, W2, Wsx, bsx, Wcx, bcx, Wsy, bsy, Wcy, bcy, Wn, bn, w1bp, w2bp, wf, bfv);

    mlp_kernel<<<NROWS / BM, 512, 0, stream>>>(
        pf, pt, nm, w1bp, w2bp, wf, bfv, b1, b2, (float*)d_out);
}

// Round 17
// 181.813 us; speedup vs baseline: 1.0096x; 1.0096x over previous
//
#include <hip/hip_runtime.h>
#include <hip/hip_bf16.h>
#include <stdint.h>

#define NROWS 131072
#define BM 128
#define NK1 20
#define NK2 16

typedef __attribute__((ext_vector_type(8))) short bf16x8;
typedef __attribute__((ext_vector_type(4))) float f32x4;
typedef __attribute__((ext_vector_type(16))) float f32x16;
typedef __attribute__((ext_vector_type(4))) int i32x4;
typedef __attribute__((ext_vector_type(2))) unsigned int u32x2;

__device__ __forceinline__ unsigned f2bf(float x) {
    union { float f; unsigned u; } v; v.f = x;
    unsigned r = v.u + 0x7FFFu + ((v.u >> 16) & 1u);
    return r >> 16;
}

__device__ __forceinline__ unsigned pk2(float a, float b) {
    float2 t; t.x = a; t.y = b;
    __hip_bfloat162 h = __float22bfloat162_rn(t);
    union { __hip_bfloat162 h; unsigned u; } c; c.h = h;
    return c.u;
}

// LDS-only barrier: order LDS writes->reads without draining vmcnt.
__device__ __forceinline__ void lds_barrier() {
    asm volatile("s_waitcnt lgkmcnt(0)" ::: "memory");
    __builtin_amdgcn_sched_barrier(0);
    __builtin_amdgcn_s_barrier();
}

// ws layout:
// [0, 655360)            W1 bf16 PACKED [wv8][ks20][cn2][s2][lane64][8]  (32x32x16 A-frag order)
// [655360, 1179648)      W2 bf16 PACKED [wv8][ks16][cn2][s2][lane64][8]
// [1179648, +2560)       wf[640] f32 (trig rows pre-scaled by 1/2pi)
// [1182208, +2560)       bfv[640] f32 (cos folded to sin, pre-scaled)

__global__ void prep_kernel(
    const float* __restrict__ W1, const float* __restrict__ W2,
    const float* __restrict__ Wsx, const float* __restrict__ bsx,
    const float* __restrict__ Wcx, const float* __restrict__ bcx,
    const float* __restrict__ Wsy, const float* __restrict__ bsy,
    const float* __restrict__ Wcy, const float* __restrict__ bcy,
    const float* __restrict__ Wn, const float* __restrict__ bn,
    unsigned short* __restrict__ w1bp, unsigned short* __restrict__ w2bp,
    float* __restrict__ wf, float* __restrict__ bfv)
{
    int i = blockIdx.x * blockDim.x + threadIdx.x;
    const int n1 = 512 * 640;
    const int n2 = 512 * 512;
    if (i < n1) {
        // A-frag for v_mfma_f32_32x32x16_bf16: row=lane&31, k=(lane>>5)*8+e
        int e = i & 7, g = i >> 3;
        int lane = g & 63;
        int s  = (g >> 6) & 1;
        int cn = (g >> 7) & 1;
        int wk = g >> 8;                 // wv*20 + ks
        int ks = wk % 20, wv = wk / 20;
        int col = wv * 64 + cn * 32 + (lane & 31);
        int k   = ks * 32 + s * 16 + (lane >> 5) * 8 + e;
        w1bp[i] = (unsigned short)f2bf(W1[col * 640 + k]);
    } else if (i < n1 + n2) {
        int ii = i - n1;
        int e = ii & 7, g = ii >> 3;
        int lane = g & 63;
        int s  = (g >> 6) & 1;
        int cn = (g >> 7) & 1;
        int ks = (g >> 8) & 15, wv = g >> 12;
        int col = wv * 64 + cn * 32 + (lane & 31);
        int k   = ks * 32 + s * 16 + (lane >> 5) * 8 + e;
        w2bp[ii] = (unsigned short)f2bf(W2[col * 512 + k]);
    }
    if (i < 640) {
        const float HPI = 1.57079632679489662f;
        const float INV2PI = 0.15915494309189535f;
        float w, b;
        if (i < 512) {
            int j = i & 63, q = (i >> 6) & 3;
            if      (q == 0) { w = Wsx[j]; b = bsx[j]; }
            else if (q == 1) { w = Wcx[j]; b = bcx[j] + HPI; }
            else if (q == 2) { w = Wsy[j]; b = bsy[j]; }
            else             { w = Wcy[j]; b = bcy[j] + HPI; }
            w *= INV2PI; b *= INV2PI;    // revolutions for raw v_sin_f32
        } else { w = Wn[i - 512]; b = bn[i - 512]; }
        wf[i] = w; bfv[i] = b;
    }
}

// LDS (unit-major, conflict-free bursts):
//   feats: unit ku=k/8 in [0,80), addr = (ku*128 + row)*16   -> 163840 B
//   h:     unit ku=col/8 in [0,64), addr = (ku*128 + row)*16 -> 131072 B (aliased)

__global__ __launch_bounds__(512, 2) void mlp_kernel(
    const float* __restrict__ pf, const float* __restrict__ pt,
    const float* __restrict__ nm,
    const unsigned short* __restrict__ w1bp,
    const unsigned short* __restrict__ w2bp,
    const float* __restrict__ wf, const float* __restrict__ bfv,
    const float* __restrict__ b1, const float* __restrict__ b2,
    float* __restrict__ out)
{
    __shared__ __align__(16) unsigned char lds[163840];

    const int tid  = threadIdx.x;
    const int lane = tid & 63;
    const int wave = tid >> 6;          // 0..7, each owns 64 output cols
    const int l31  = lane & 31;
    const int l32  = lane >> 5;         // 0..1
    const int rowbase = blockIdx.x * BM;
    const int wcol = wave * 64;

    // encode mapping: row = tid&127, g = tid>>7; per-wave writes contiguous
    const int erow = tid & 127;
    const int g    = tid >> 7;          // 0..3
    const int grow = rowbase + erow;
    const float v0 = pf[grow * 2 + 0];
    const float v1 = pf[grow * 2 + 1];
    const float v2 = pt[grow * 2 + 0];
    const float v3 = pt[grow * 2 + 1];
    const float v4 = nm[grow];

    const unsigned short* w1p = w1bp + wave * (NK1 * 4 * 512) + lane * 8;
    const unsigned short* w2p = w2bp + wave * (NK2 * 4 * 512) + lane * 8;
#define W1FRAG(KS, CN, S) (*(const bf16x8*)(w1p + (((KS) * 4 + (CN) * 2 + (S)) * 512)))
#define W2FRAG(KS, CN, S) (*(const bf16x8*)(w2p + (((KS) * 4 + (CN) * 2 + (S)) * 512)))
// B-frag reads: activation-row = rn*32+l31, k-unit = ks*4 + s*2 + l32 (contiguous burst)
#define LDS_AF(KS, S, RN) (*(const bf16x8*)(lds + \
        ((((KS) * 4 + (S) * 2 + l32) * 128 + (RN) * 32 + l31) << 4)))
#define LDS_HF(KS, S, RN) LDS_AF(KS, S, RN)

    // depth-2 rotating W-fragment buffers: [parity][cn][s]
    bf16x8 wb[2][2][2];
    #pragma unroll
    for (int p = 0; p < 2; ++p)
        #pragma unroll
        for (int cn = 0; cn < 2; ++cn)
            #pragma unroll
            for (int s = 0; s < 2; ++s)
                wb[p][cn][s] = W1FRAG(p, cn, s);

    // ---------------- encode: units ku = g + j*4, j = 0..19 ----------------
    // segment per j compile-time: j0-3 pf.x | j4-7 pf.y | j8-11 pt.x |
    // j12-15 pt.y | j16-19 numbers ; native v_sin for j<16 (pre-scaled).
    {
        #pragma unroll
        for (int j = 0; j < 20; ++j) {
            const int ku = g + j * 4;
            const int k = ku * 8;
            const float xv = (j < 4) ? v0 : (j < 8) ? v1 :
                             (j < 12) ? v2 : (j < 16) ? v3 : v4;
            const f32x4 w0 = *(const f32x4*)(wf + k);
            const f32x4 w1v = *(const f32x4*)(wf + k + 4);
            const f32x4 c0 = *(const f32x4*)(bfv + k);
            const f32x4 c1 = *(const f32x4*)(bfv + k + 4);
            float r[8];
            #pragma unroll
            for (int t = 0; t < 4; ++t) {
                float a0 = fmaf(xv, w0[t], c0[t]);
                float a1 = fmaf(xv, w1v[t], c1[t]);
                if (j < 16) {
                    asm("v_sin_f32 %0, %1" : "=v"(r[t])     : "v"(a0));
                    asm("v_sin_f32 %0, %1" : "=v"(r[t + 4]) : "v"(a1));
                } else { r[t] = a0; r[t + 4] = a1; }
            }
            i32x4 pk;
            pk.x = (int)pk2(r[0], r[1]);
            pk.y = (int)pk2(r[2], r[3]);
            pk.z = (int)pk2(r[4], r[5]);
            pk.w = (int)pk2(r[6], r[7]);
            *(i32x4*)(lds + ((ku * 128 + erow) << 4)) = pk;
        }
    }

    f32x16 acc[4][2];
    #pragma unroll
    for (int a = 0; a < 4; ++a)
        #pragma unroll
        for (int b = 0; b < 2; ++b) acc[a][b] = (f32x16)(0.0f);

    lds_barrier();   // feats visible; W prefetches stay in flight

    // ---------------- layer 1: K=640, 32x32x16 MFMA, depth-2 W rotation --------
    #pragma unroll
    for (int ks = 0; ks < NK1; ++ks) {
        const int cur = ks & 1;
        __builtin_amdgcn_s_setprio(1);
        #pragma unroll
        for (int s = 0; s < 2; ++s) {
            #pragma unroll
            for (int rn = 0; rn < 4; ++rn) {
                bf16x8 af = LDS_AF(ks, s, rn);
                #pragma unroll
                for (int cn = 0; cn < 2; ++cn)
                    acc[rn][cn] = __builtin_amdgcn_mfma_f32_32x32x16_bf16(
                        wb[cur][cn][s], af, acc[rn][cn], 0, 0, 0);
            }
        }
        __builtin_amdgcn_s_setprio(0);
        if (ks + 2 < NK1) {
            #pragma unroll
            for (int cn = 0; cn < 2; ++cn)
                #pragma unroll
                for (int s = 0; s < 2; ++s)
                    wb[cur][cn][s] = W1FRAG(ks + 2, cn, s);
        } else {
            #pragma unroll
            for (int cn = 0; cn < 2; ++cn)
                #pragma unroll
                for (int s = 0; s < 2; ++s)
                    wb[cur][cn][s] = W2FRAG(ks + 2 - NK1, cn, s);
        }
    }

    lds_barrier();   // all feats reads done; h may alias feats

    // ---------------- bias + leaky -> h (unit-major, contiguous 8B writes) -----
    // C/D: row = rn*32 + l31; col = wcol + cn*32 + rg*8 + l32*4 + 0..3
    #pragma unroll
    for (int rn = 0; rn < 4; ++rn) {
        const int row = rn * 32 + l31;
        #pragma unroll
        for (int cn = 0; cn < 2; ++cn) {
            #pragma unroll
            for (int rg = 0; rg < 4; ++rg) {
                const int colb = wcol + cn * 32 + rg * 8 + l32 * 4;
                const f32x4 bb = *(const f32x4*)(b1 + colb);
                float h0 = acc[rn][cn][rg * 4 + 0] + bb[0];
                float h1 = acc[rn][cn][rg * 4 + 1] + bb[1];
                float h2 = acc[rn][cn][rg * 4 + 2] + bb[2];
                float h3 = acc[rn][cn][rg * 4 + 3] + bb[3];
                h0 = (h0 >= 0.f) ? h0 : 0.01f * h0;
                h1 = (h1 >= 0.f) ? h1 : 0.01f * h1;
                h2 = (h2 >= 0.f) ? h2 : 0.01f * h2;
                h3 = (h3 >= 0.f) ? h3 : 0.01f * h3;
                u32x2 pk;
                pk.x = pk2(h0, h1);
                pk.y = pk2(h2, h3);
                const int ku = wave * 8 + cn * 4 + rg;   // col/8
                *(u32x2*)(lds + ((ku * 128 + row) << 4) + l32 * 8) = pk;
            }
        }
    }

    #pragma unroll
    for (int a = 0; a < 4; ++a)
        #pragma unroll
        for (int b = 0; b < 2; ++b) acc[a][b] = (f32x16)(0.0f);

    lds_barrier();   // h visible

    // ---------------- layer 2: K=512 ----------------
    #pragma unroll
    for (int ks = 0; ks < NK2; ++ks) {
        const int cur = ks & 1;
        __builtin_amdgcn_s_setprio(1);
        #pragma unroll
        for (int s = 0; s < 2; ++s) {
            #pragma unroll
            for (int rn = 0; rn < 4; ++rn) {
                bf16x8 hf = LDS_HF(ks, s, rn);
                #pragma unroll
                for (int cn = 0; cn < 2; ++cn)
                    acc[rn][cn] = __builtin_amdgcn_mfma_f32_32x32x16_bf16(
                        wb[cur][cn][s], hf, acc[rn][cn], 0, 0, 0);
            }
        }
        __builtin_amdgcn_s_setprio(0);
        if (ks + 2 < NK2) {
            #pragma unroll
            for (int cn = 0; cn < 2; ++cn)
                #pragma unroll
                for (int s = 0; s < 2; ++s)
                    wb[cur][cn][s] = W2FRAG(ks + 2, cn, s);
        }
    }

    // ---------------- epilogue: bias + float4 stores ----------------
    #pragma unroll
    for (int rn = 0; rn < 4; ++rn) {
        const int row = rowbase + rn * 32 + l31;
        #pragma unroll
        for (int cn = 0; cn < 2; ++cn) {
            #pragma unroll
            for (int rg = 0; rg < 4; ++rg) {
                const int colb = wcol + cn * 32 + rg * 8 + l32 * 4;
                const f32x4 bb = *(const f32x4*)(b2 + colb);
                f32x4 o;
                o.x = acc[rn][cn][rg * 4 + 0] + bb[0];
                o.y = acc[rn][cn][rg * 4 + 1] + bb[1];
                o.z = acc[rn][cn][rg * 4 + 2] + bb[2];
                o.w = acc[rn][cn][rg * 4 + 3] + bb[3];
                *(f32x4*)(out + row * 512 + colb) = o;
            }
        }
    }
}

extern "C" void kernel_launch(void* const* d_in, const int* in_sizes, int n_in,
                              void* d_out, int out_size, void* d_ws, size_t ws_size,
                              hipStream_t stream)
{
    (void)in_sizes; (void)n_in; (void)out_size; (void)ws_size;
    const float* pf  = (const float*)d_in[0];
    const float* pt  = (const float*)d_in[1];
    const float* nm  = (const float*)d_in[2];
    const float* Wsx = (const float*)d_in[3];
    const float* bsx = (const float*)d_in[4];
    const float* Wcx = (const float*)d_in[5];
    const float* bcx = (const float*)d_in[6];
    const float* Wsy = (const float*)d_in[7];
    const float* bsy = (const float*)d_in[8];
    const float* Wcy = (const float*)d_in[9];
    const float* bcy = (const float*)d_in[10];
    const float* Wn  = (const float*)d_in[11];
    const float* bn  = (const float*)d_in[12];
    const float* W1  = (const float*)d_in[13];
    const float* b1  = (const float*)d_in[14];
    const float* W2  = (const float*)d_in[15];
    const float* b2  = (const float*)d_in[16];

    unsigned char* ws = (unsigned char*)d_ws;
    unsigned short* w1bp = (unsigned short*)(ws);
    unsigned short* w2bp = (unsigned short*)(ws + 512 * 640 * 2);
    float* wf  = (float*)(ws + 512 * 640 * 2 + 512 * 512 * 2);
    float* bfv = (float*)(ws + 512 * 640 * 2 + 512 * 512 * 2 + 640 * 4);

    const int prep_threads = 512 * 640 + 512 * 512;
    prep_kernel<<<(prep_threads + 255) / 256, 256, 0, stream>>>(
        W1, W2, Wsx, bsx, Wcx, bcx, Wsy, bsy, Wcy, bcy, Wn, bn, w1bp, w2bp, wf, bfv);

    mlp_kernel<<<NROWS / BM, 512, 0, stream>>>(
        pf, pt, nm, w1bp, w2bp, wf, bfv, b1, b2, (float*)d_out);
}